// Round 7
// baseline (266.665 us; speedup 1.0000x reference)
//
#include <hip/hip_runtime.h>

#define N 4096
#define D 256
#define MARGIN 0.3f
#define BIG 10000.0f
#define NBLK 4096          // 64x64 grid of 64x64 tiles

typedef _Float16 f16x8 __attribute__((ext_vector_type(8)));
typedef _Float16 f16x4 __attribute__((ext_vector_type(4)));
typedef float floatx16 __attribute__((ext_vector_type(16)));

__device__ inline void atomicMaxFloatPos(float* a, float v) {
    atomicMax((int*)a, __float_as_int(v));   // valid: all values >= 0
}
__device__ inline void atomicMinFloatPos(float* a, float v) {
    atomicMin((int*)a, __float_as_int(v));
}

// Wave per row: convert x -> fp16 Xf (RNE), sq from the CONVERTED values
// (so the Gram diagonal cancels exactly), init ap/ang/anl + done-counter.
__global__ __launch_bounds__(256) void prep_kernel(const float* __restrict__ x,
                                                   float* __restrict__ sq,
                                                   _Float16* __restrict__ Xf,
                                                   float* ap, float* ang, float* anl,
                                                   unsigned* counter) {
    const int wave = threadIdx.x >> 6, lane = threadIdx.x & 63;
    const int row = blockIdx.x * 4 + wave;
    const float4 v = *(const float4*)(x + (size_t)row * D + lane * 4);
    f16x4 h;
    h[0] = (_Float16)v.x; h[1] = (_Float16)v.y;
    h[2] = (_Float16)v.z; h[3] = (_Float16)v.w;
    *(f16x4*)(Xf + (size_t)row * D + lane * 4) = h;
    const float c0 = (float)h[0], c1 = (float)h[1], c2 = (float)h[2], c3 = (float)h[3];
    float s = c0 * c0 + c1 * c1 + c2 * c2 + c3 * c3;
    #pragma unroll
    for (int off = 32; off; off >>= 1) s += __shfl_down(s, off);
    if (lane == 0) sq[row] = s;
    if (threadIdx.x < 4) {
        const int i = blockIdx.x * 4 + threadIdx.x;
        ap[i] = 0.0f; ang[i] = BIG; anl[i] = BIG;
    }
    if (blockIdx.x == 0 && threadIdx.x == 0) *counter = 0u;
}

// One wave per 64x64 tile. ZERO LDS, zero barriers: MFMA fragments are
// loaded DIRECTLY from global (L2-resident 2 MB Xf) as dwordx4 with
// immediate offsets. Epilogue: d = sqrt(..), coalesced dword stores,
// half-wave xor-shuffle reduction, 3 atomics per row. Last block (device
// atomic counter) computes hist + loss/cnt and writes the scalars.
__global__ __launch_bounds__(64, 3) void dist_kernel(const _Float16* __restrict__ Xf,
                                                     const int* __restrict__ tgt,
                                                     const float* __restrict__ sq,
                                                     float* __restrict__ dist,
                                                     float* ap, float* ang, float* anl,
                                                     unsigned* counter,
                                                     float* __restrict__ out) {
    const int lane = threadIdx.x;
    const int row0 = blockIdx.y * 64;
    const int col0 = blockIdx.x * 64;

    // Fragment addressing for mfma_f32_32x32x16_f16 (verified R5):
    // lane holds A[m = lane&31][k = (lane>>5)*8 + j], j=0..7 -> one 16B chunk.
    const int ar = lane & 31;
    const int kh = (lane >> 5) * 8;
    const _Float16* pa0 = Xf + (size_t)(row0 + ar) * D + kh;
    const _Float16* pa1 = pa0 + (size_t)32 * D;
    const _Float16* pb0 = Xf + (size_t)(col0 + ar) * D + kh;
    const _Float16* pb1 = pb0 + (size_t)32 * D;

    floatx16 acc[2][2];
    #pragma unroll
    for (int mt = 0; mt < 2; ++mt)
        #pragma unroll
        for (int nt = 0; nt < 2; ++nt)
            #pragma unroll
            for (int r = 0; r < 16; ++r) acc[mt][nt][r] = 0.0f;

    #pragma unroll
    for (int ks = 0; ks < 16; ++ks) {
        const f16x8 a0 = *(const f16x8*)(pa0 + ks * 16);
        const f16x8 a1 = *(const f16x8*)(pa1 + ks * 16);
        const f16x8 b0 = *(const f16x8*)(pb0 + ks * 16);
        const f16x8 b1 = *(const f16x8*)(pb1 + ks * 16);
        acc[0][0] = __builtin_amdgcn_mfma_f32_32x32x16_f16(a0, b0, acc[0][0], 0, 0, 0);
        acc[0][1] = __builtin_amdgcn_mfma_f32_32x32x16_f16(a0, b1, acc[0][1], 0, 0, 0);
        acc[1][0] = __builtin_amdgcn_mfma_f32_32x32x16_f16(a1, b0, acc[1][0], 0, 0, 0);
        acc[1][1] = __builtin_amdgcn_mfma_f32_32x32x16_f16(a1, b1, acc[1][1], 0, 0, 0);
    }

    // Epilogue. C/D layout: col = lane&31, row = (r&3) + 8*(r>>2) + 4*(lane>>5).
    const int gc0 = col0 + ar, gc1 = col0 + 32 + ar;
    const float sqc0 = sq[gc0], sqc1 = sq[gc1];
    const int tc0 = tgt[gc0], tc1 = tgt[gc1];
    const int rl_base = 4 * (lane >> 5);

    #pragma unroll
    for (int mt = 0; mt < 2; ++mt) {
        #pragma unroll
        for (int r = 0; r < 16; ++r) {
            const int row_l = mt * 32 + (r & 3) + 8 * (r >> 2) + rl_base;
            const int grow  = row0 + row_l;
            const float sqi = sq[grow];
            const int   ti  = tgt[grow];
            const float d0 = sqrtf(fmaxf(sqi + sqc0 - 2.0f * acc[mt][0][r], 0.0f));
            const float d1 = sqrtf(fmaxf(sqi + sqc1 - 2.0f * acc[mt][1][r], 0.0f));
            dist[(size_t)grow * N + gc0] = d0;
            dist[(size_t)grow * N + gc1] = d1;
            float mx = 0.0f, mg = BIG, ml = BIG;
            if (tc0 == ti)      mx = d0;
            else if (tc0 > ti)  mg = d0;
            else                ml = d0;
            if (tc1 == ti)      mx = fmaxf(mx, d1);
            else if (tc1 > ti)  mg = fminf(mg, d1);
            else                ml = fminf(ml, d1);
            // reduce across the 32 lanes of this half-wave (same row)
            #pragma unroll
            for (int off = 1; off < 32; off <<= 1) {
                mx = fmaxf(mx, __shfl_xor(mx, off, 32));
                mg = fminf(mg, __shfl_xor(mg, off, 32));
                ml = fminf(ml, __shfl_xor(ml, off, 32));
            }
            if (ar == 0) {
                atomicMaxFloatPos(&ap[grow], mx);
                atomicMinFloatPos(&ang[grow], mg);
                atomicMinFloatPos(&anl[grow], ml);
            }
        }
    }

    // ---- Last-block finish (device-scope counter). ----
    __threadfence();
    unsigned done = 0;
    if (lane == 0) done = atomicAdd(counter, 1u);
    done = __shfl(done, 0);
    if (done != NBLK - 1) return;
    __threadfence();

    // Histogram of 4096 labels across 64 lanes (coalesced).
    int c0 = 0, c1 = 0, c2 = 0, c3 = 0;
    #pragma unroll 4
    for (int j = 0; j < 64; ++j) {
        const int lab = tgt[j * 64 + lane] & 3;
        c0 += (lab == 0); c1 += (lab == 1); c2 += (lab == 2); c3 += (lab == 3);
    }
    #pragma unroll
    for (int off = 32; off; off >>= 1) {
        c0 += __shfl_xor(c0, off); c1 += __shfl_xor(c1, off);
        c2 += __shfl_xor(c2, off); c3 += __shfl_xor(c3, off);
    }
    const int hist[4] = {c0, c1, c2, c3};

    float term = 0.0f; int cc = 0;
    #pragma unroll 4
    for (int j = 0; j < 64; ++j) {
        const int i = j * 64 + lane;
        term += fmaxf(ap[i] - fabsf(ang[i] - anl[i]) + MARGIN, 0.0f);
        cc += (hist[tgt[i] & 3] == 1) ? 1 : 0;
    }
    #pragma unroll
    for (int off = 32; off; off >>= 1) {
        term += __shfl_down(term, off);
        cc   += __shfl_down(cc, off);
    }
    if (lane == 0) {
        out[0] = term * (1.0f / N);
        out[1 + (size_t)N * N] = (float)cc;
    }
}

extern "C" void kernel_launch(void* const* d_in, const int* in_sizes, int n_in,
                              void* d_out, int out_size, void* d_ws, size_t ws_size,
                              hipStream_t stream) {
    const float* x   = (const float*)d_in[0];
    const int*   tgt = (const int*)d_in[1];
    float* out = (float*)d_out;
    char*  ws  = (char*)d_ws;

    _Float16* Xf  = (_Float16*)ws;                    // 2 MiB, 16B-aligned
    float*    sq  = (float*)(ws + 2097152);
    float*    ap  = sq + 4096;
    float*    ang = sq + 8192;
    float*    anl = sq + 12288;
    unsigned* cnt = (unsigned*)(sq + 16384);

    prep_kernel<<<N / 4, 256, 0, stream>>>(x, sq, Xf, ap, ang, anl, cnt);
    dim3 grid(N / 64, N / 64);
    dist_kernel<<<grid, 64, 0, stream>>>(Xf, tgt, sq, out + 1, ap, ang, anl, cnt, out);
}

// Round 8
// 242.549 us; speedup vs baseline: 1.0994x; 1.0994x over previous
//
#include <hip/hip_runtime.h>

#define N 4096
#define D 256
#define MARGIN 0.3f
#define BIG 10000.0f
#define NBLK 4096          // 64x64 grid of 64x64 tiles

typedef _Float16 f16x8 __attribute__((ext_vector_type(8)));
typedef _Float16 f16x4 __attribute__((ext_vector_type(4)));
typedef float floatx16 __attribute__((ext_vector_type(16)));

__device__ inline void atomicMaxFloatPos(float* a, float v) {
    atomicMax((int*)a, __float_as_int(v));   // valid: all values >= 0
}
__device__ inline void atomicMinFloatPos(float* a, float v) {
    atomicMin((int*)a, __float_as_int(v));
}

// async 16B global -> LDS (wave-uniform LDS base + lane*16)
__device__ inline void gl_lds16(const void* g, void* l) {
    __builtin_amdgcn_global_load_lds(
        (const __attribute__((address_space(1))) unsigned int*)g,
        (__attribute__((address_space(3))) unsigned int*)l, 16, 0, 0);
}

// Wave per row: convert x -> fp16 Xf (RNE), sq from the CONVERTED values
// (so the Gram diagonal cancels exactly), init ap/ang/anl + done-counter.
__global__ __launch_bounds__(256) void prep_kernel(const float* __restrict__ x,
                                                   float* __restrict__ sq,
                                                   _Float16* __restrict__ Xf,
                                                   float* ap, float* ang, float* anl,
                                                   unsigned* counter) {
    const int wave = threadIdx.x >> 6, lane = threadIdx.x & 63;
    const int row = blockIdx.x * 4 + wave;
    const float4 v = *(const float4*)(x + (size_t)row * D + lane * 4);
    f16x4 h;
    h[0] = (_Float16)v.x; h[1] = (_Float16)v.y;
    h[2] = (_Float16)v.z; h[3] = (_Float16)v.w;
    *(f16x4*)(Xf + (size_t)row * D + lane * 4) = h;
    const float c0 = (float)h[0], c1 = (float)h[1], c2 = (float)h[2], c3 = (float)h[3];
    float s = c0 * c0 + c1 * c1 + c2 * c2 + c3 * c3;
    #pragma unroll
    for (int off = 32; off; off >>= 1) s += __shfl_down(s, off);
    if (lane == 0) sq[row] = s;
    if (threadIdx.x < 4) {
        const int i = blockIdx.x * 4 + threadIdx.x;
        ap[i] = 0.0f; ang[i] = BIG; anl[i] = BIG;
    }
    if (blockIdx.x == 0 && threadIdx.x == 0) *counter = 0u;
}

// One wave (64 threads) per 64x64 output tile — R5-proven core.
// Wave-private 16 KB LDS, NO barriers. 4 stages of BK=64 staged via
// global_load_lds (contiguous 1 KB per instr), manual vmcnt(0) per stage.
// LDS row = 128 B = 8 chunks of 16 B; logical chunk q of row r stored at
// phys q ^ (r&7) (conflict-free ds_read_b128).
// Epilogue: phase A computes d, NONTEMPORAL coalesced global stores +
// swizzled LDS f32 tile; phase B: lane = row, serial reduce, 3 atomics.
// Last block (device atomic counter) computes hist + loss/cnt scalars.
__global__ __launch_bounds__(64) void dist_kernel(const _Float16* __restrict__ Xf,
                                                  const int* __restrict__ tgt,
                                                  const float* __restrict__ sq,
                                                  float* __restrict__ dist,
                                                  float* ap, float* ang, float* anl,
                                                  unsigned* counter,
                                                  float* __restrict__ out) {
    __shared__ _Float16 lds[8192];          // 16 KiB total
    _Float16* ldsA = lds;                   // 64 x 64 fp16 (8 KiB)
    _Float16* ldsB = lds + 4096;            // 64 x 64 fp16 (8 KiB)
    float*    ldsC = (float*)lds;           // epilogue: 64 x 64 f32 (16 KiB)

    const int lane = threadIdx.x;
    const int row0 = blockIdx.y * 64;
    const int col0 = blockIdx.x * 64;

    // DMA source mapping: lane -> row-in-8-group (drow), phys chunk (lane&7);
    // fetch logical chunk q = (lane&7) ^ drow so frag reads are conflict-free.
    const int drow = lane >> 3;                    // 0..7
    const int q    = (lane & 7) ^ drow;            // logical chunk 0..7

    floatx16 acc[2][2];
    #pragma unroll
    for (int mt = 0; mt < 2; ++mt)
        #pragma unroll
        for (int nt = 0; nt < 2; ++nt)
            #pragma unroll
            for (int r = 0; r < 16; ++r) acc[mt][nt][r] = 0.0f;

    const int m0 = lane & 31;
    const int m1 = 32 + m0;

    for (int s = 0; s < 4; ++s) {
        const int k0 = s * 64;
        // ensure prior stage's LDS reads retired before DMA overwrites
        __asm__ volatile("s_waitcnt lgkmcnt(0)" ::: "memory");
        #pragma unroll
        for (int d = 0; d < 8; ++d) {
            const int r = d * 8 + drow;
            gl_lds16(Xf + (size_t)(row0 + r) * D + k0 + q * 8, ldsA + d * 512);
            gl_lds16(Xf + (size_t)(col0 + r) * D + k0 + q * 8, ldsB + d * 512);
        }
        __asm__ volatile("s_waitcnt vmcnt(0)" ::: "memory");

        #pragma unroll
        for (int ks = 0; ks < 4; ++ks) {
            const int lq = ks * 2 + (lane >> 5);   // logical quad 0..7
            f16x8 a0 = *(const f16x8*)(ldsA + m0 * 64 + ((lq ^ (m0 & 7)) << 3));
            f16x8 a1 = *(const f16x8*)(ldsA + m1 * 64 + ((lq ^ (m1 & 7)) << 3));
            f16x8 b0 = *(const f16x8*)(ldsB + m0 * 64 + ((lq ^ (m0 & 7)) << 3));
            f16x8 b1 = *(const f16x8*)(ldsB + m1 * 64 + ((lq ^ (m1 & 7)) << 3));
            acc[0][0] = __builtin_amdgcn_mfma_f32_32x32x16_f16(a0, b0, acc[0][0], 0, 0, 0);
            acc[0][1] = __builtin_amdgcn_mfma_f32_32x32x16_f16(a0, b1, acc[0][1], 0, 0, 0);
            acc[1][0] = __builtin_amdgcn_mfma_f32_32x32x16_f16(a1, b0, acc[1][0], 0, 0, 0);
            acc[1][1] = __builtin_amdgcn_mfma_f32_32x32x16_f16(a1, b1, acc[1][1], 0, 0, 0);
        }
        __asm__ volatile("" ::: "memory");   // pin stage ordering
    }

    // ---- Epilogue phase A: d = sqrt(sqi + sqj - 2*dot); nontemporal global
    // stores + swizzled LDS f32 tile. C/D layout: col = lane&31,
    // row = (r&3) + 8*(r>>2) + 4*(lane>>5).
    const int gc0 = col0 + m0, gc1 = col0 + 32 + m0;
    const float sqc0 = sq[gc0], sqc1 = sq[gc1];
    const int rl_base = 4 * (lane >> 5);

    #pragma unroll
    for (int mt = 0; mt < 2; ++mt) {
        #pragma unroll
        for (int r = 0; r < 16; ++r) {
            const int row_l = mt * 32 + (r & 3) + 8 * (r >> 2) + rl_base;
            const int grow  = row0 + row_l;
            const float sqi = sq[grow];
            const float d0 = sqrtf(fmaxf(sqi + sqc0 - 2.0f * acc[mt][0][r], 0.0f));
            const float d1 = sqrtf(fmaxf(sqi + sqc1 - 2.0f * acc[mt][1][r], 0.0f));
            __builtin_nontemporal_store(d0, &dist[(size_t)grow * N + gc0]);
            __builtin_nontemporal_store(d1, &dist[(size_t)grow * N + gc1]);
            const int sw = row_l & 15;
            ldsC[row_l * 64 + (((m0 >> 2) ^ sw) << 2) + (m0 & 3)] = d0;
            ldsC[row_l * 64 + ((((m0 + 32) >> 2) ^ sw) << 2) + (m0 & 3)] = d1;
        }
    }
    __asm__ volatile("s_waitcnt lgkmcnt(0)" ::: "memory");

    // ---- Phase B: lane = row, serial reduce over 64 cols, 3 atomics.
    const int grow = row0 + lane;
    const int ti   = tgt[grow];
    float mx = 0.0f, mg = BIG, ml = BIG;
    #pragma unroll
    for (int j = 0; j < 16; ++j) {
        const int4  t4 = *(const int4*)&tgt[col0 + j * 4];    // uniform addr
        const float4 d4 = *(const float4*)&ldsC[lane * 64 + ((j ^ (lane & 15)) << 2)];
        if (t4.x == ti) mx = fmaxf(mx, d4.x); else if (t4.x > ti) mg = fminf(mg, d4.x); else ml = fminf(ml, d4.x);
        if (t4.y == ti) mx = fmaxf(mx, d4.y); else if (t4.y > ti) mg = fminf(mg, d4.y); else ml = fminf(ml, d4.y);
        if (t4.z == ti) mx = fmaxf(mx, d4.z); else if (t4.z > ti) mg = fminf(mg, d4.z); else ml = fminf(ml, d4.z);
        if (t4.w == ti) mx = fmaxf(mx, d4.w); else if (t4.w > ti) mg = fminf(mg, d4.w); else ml = fminf(ml, d4.w);
    }
    atomicMaxFloatPos(&ap[grow], mx);
    atomicMinFloatPos(&ang[grow], mg);
    atomicMinFloatPos(&anl[grow], ml);

    // ---- Last-block finish (device-scope counter, R7-proven). ----
    __threadfence();
    unsigned done = 0;
    if (lane == 0) done = atomicAdd(counter, 1u);
    done = __shfl(done, 0);
    if (done != NBLK - 1) return;
    __threadfence();

    // Histogram of 4096 labels across 64 lanes (coalesced).
    int c0 = 0, c1 = 0, c2 = 0, c3 = 0;
    #pragma unroll 4
    for (int j = 0; j < 64; ++j) {
        const int lab = tgt[j * 64 + lane] & 3;
        c0 += (lab == 0); c1 += (lab == 1); c2 += (lab == 2); c3 += (lab == 3);
    }
    #pragma unroll
    for (int off = 32; off; off >>= 1) {
        c0 += __shfl_xor(c0, off); c1 += __shfl_xor(c1, off);
        c2 += __shfl_xor(c2, off); c3 += __shfl_xor(c3, off);
    }
    const int hist[4] = {c0, c1, c2, c3};

    float term = 0.0f; int cc = 0;
    #pragma unroll 4
    for (int j = 0; j < 64; ++j) {
        const int i = j * 64 + lane;
        term += fmaxf(ap[i] - fabsf(ang[i] - anl[i]) + MARGIN, 0.0f);
        cc += (hist[tgt[i] & 3] == 1) ? 1 : 0;
    }
    #pragma unroll
    for (int off = 32; off; off >>= 1) {
        term += __shfl_down(term, off);
        cc   += __shfl_down(cc, off);
    }
    if (lane == 0) {
        out[0] = term * (1.0f / N);
        out[1 + (size_t)N * N] = (float)cc;
    }
}

extern "C" void kernel_launch(void* const* d_in, const int* in_sizes, int n_in,
                              void* d_out, int out_size, void* d_ws, size_t ws_size,
                              hipStream_t stream) {
    const float* x   = (const float*)d_in[0];
    const int*   tgt = (const int*)d_in[1];
    float* out = (float*)d_out;
    char*  ws  = (char*)d_ws;

    _Float16* Xf  = (_Float16*)ws;                    // 2 MiB, 16B-aligned
    float*    sq  = (float*)(ws + 2097152);
    float*    ap  = sq + 4096;
    float*    ang = sq + 8192;
    float*    anl = sq + 12288;
    unsigned* cnt = (unsigned*)(sq + 16384);

    prep_kernel<<<N / 4, 256, 0, stream>>>(x, sq, Xf, ap, ang, anl, cnt);
    dim3 grid(N / 64, N / 64);
    dist_kernel<<<grid, 64, 0, stream>>>(Xf, tgt, sq, out + 1, ap, ang, anl, cnt, out);
}